// Round 4
// baseline (360.413 us; speedup 1.0000x reference)
//
#include <hip/hip_runtime.h>
#include <math.h>

#define NS 68
#define BLOCK 256
#define F4_PER_ROW 17      // 68 / 4
#define EPSC 1e-10f

// Round 4: NO LDS, one row per thread, pure registers.
//  - 17 independent float4 loads (uncoalesced 16B/lane but line-merged by
//    L1/L2 MSHRs: 4 consecutive k's of a thread share each 64B line; region
//    is dense so HBM traffic stays ~ideal — round-3 FETCH confirmed).
//  - launch_bounds(256,2): 256-VGPR cap so the compiler never spills and,
//    unlike rounds 1-2 (92-VGPR heuristic), can keep ALL 17 loads in flight.
//  - Stores interleaved with compute: each float4 group of d stored as soon
//    as ready (only d61/d67 held across sections) -> no 68-wide d[] bulge
//    at the end (round-3's spill cause). Write-combining in L1/L2 merges the
//    4x16B per line; every byte of the row is written -> full-line evictions.
__global__ __launch_bounds__(BLOCK, 2) void MAPKPI3KODE_rhs_kernel(
    const float* __restrict__ y,
    const float* __restrict__ params,
    float* __restrict__ out)
{
    const int row = blockIdx.x * BLOCK + threadIdx.x;
    const long base4 = (long)row * F4_PER_ROW;

    const float4* __restrict__ y4 = (const float4*)y;
    float4* __restrict__ out4 = (float4*)out;

    // ---- 17 independent loads, all in flight together ----
    float4 v[F4_PER_ROW];
    #pragma unroll
    for (int k = 0; k < F4_PER_ROW; ++k) v[k] = y4[base4 + k];

    float Y[NS];
    #pragma unroll
    for (int k = 0; k < F4_PER_ROW; ++k) {
        Y[4*k+0] = fmaxf(v[k].x, 0.0f);
        Y[4*k+1] = fmaxf(v[k].y, 0.0f);
        Y[4*k+2] = fmaxf(v[k].z, 0.0f);
        Y[4*k+3] = fmaxf(v[k].w, 0.0f);
    }

    // ---- params (uniform scalar loads) ----
    const float ka1             = params[0];
    const float kr1             = params[1];
    const float kc1             = params[2];
    const float kpCraf          = params[3];
    const float kpMek           = params[4];
    const float kpErk           = params[5];
    const float kDegradEgfr     = params[6];
    const float kErkInbEgfr     = params[7];
    const float kShcDephos      = params[8];
    const float kptpDeg         = params[9];
    const float kGrb2CombShc    = params[10];
    const float kSprtyInbGrb2   = params[11];
    const float kSosCombGrb2    = params[12];
    const float kErkPhosSos     = params[13];
    const float kErkPhosPcraf   = params[14];
    const float kPcrafDegrad    = params[15];
    const float kErkPhosMek     = params[16];
    const float kMekDegrad      = params[17];
    const float kDuspInbErk     = params[18];
    const float kErkDeg         = params[19];
    const float kinbBraf        = params[20];
    const float kDuspStop       = params[21];
    const float kDusps          = params[22];
    const float kSproutyForm    = params[23];
    const float kSprtyComeDown  = params[24];
    const float kdegrad         = params[25];
    const float km_Dusp         = params[27];
    const float km_Sprty        = params[28];
    const float kErkDephos      = params[29];
    const float kDuspDeg        = params[30];
    const float kHer2_act       = params[31];
    const float kHer3_act       = params[32];
    const float k_p85_bind_EGFR = params[33];
    const float k_p85_bind_Her2 = params[34];
    const float k_p85_bind_Her3 = params[35];
    const float k_p85_bind_IGFR = params[36];
    const float k_p85_unbind    = params[37];
    const float k_PI3K_recruit  = params[38];
    const float kMTOR_Feedback  = params[39];
    const float k_PIP2_to_PIP3  = params[40];
    const float k_PTEN          = params[41];
    const float kAkt            = params[42];
    const float kdegradAKT      = params[43];
    const float kb1             = params[44];
    const float k43b1           = params[45];
    const float k4ebp1          = params[46];
    const float k_4EBP1_dephos  = params[47];
    const float kKSRphos        = params[48];
    const float kKSRdephos      = params[49];
    const float kMekByBraf      = params[50];
    const float kMekByCraf      = params[51];
    const float kMekByKSR       = params[52];
    const float Tram            = params[53];
    const float K_tram_KSR      = params[55];
    const float n_tram          = params[56];
    const float Vemurafenib     = params[57];
    const float kDimerForm      = params[58];
    const float kDimerDissoc    = params[59];
    const float kParadoxCRAF    = params[60];
    const float IC50_vem        = params[61];
    const float Hill_n_vem      = params[62];
    const float kPDGFR_act      = params[63];
    const float k_p85_bind_PDGFR= params[64];
    const float kS6K_phos       = params[65];
    const float kS6K_dephos     = params[66];
    const float kRAS_PI3K       = params[67];
    const float kERK_IRS_inhibit   = params[68];
    const float kERK_PTEN_activate = params[69];
    const float kAKT_CRAF_inhibit  = params[70];
    const float kS6K_IRS_inhibit   = params[71];
    const float kERK_GAB1_inhibit  = params[72];
    const float kAKT_TSC2_phos     = params[73];
    const float kERK_RSK_activate  = params[74];

    // uniform precomputes
    const float IC50_n   = powf(IC50_vem, Hill_n_vem);
    const float Vem_n    = powf(Vemurafenib, Hill_n_vem);
    const float kBRAF_eff = ka1 * IC50_n / (IC50_n + Vem_n + EPSC);
    const float Ktram_n  = powf(K_tram_KSR, n_tram);
    const float tram_n   = powf(Tram, n_tram);
    const float tram_ksr = Ktram_n / (Ktram_n + tram_n + EPSC);

#define STORE4(g, a, b, c, dd) do { \
        float4 _o; _o.x = (a); _o.y = (b); _o.z = (c); _o.w = (dd); \
        out4[base4 + (g)] = _o; } while (0)

    // --- EGFR / Her2 / Her3 receptor modules ---
    {
        const float d0 = -ka1*Y[0] + kr1*Y[1];
        const float d1 =  ka1*Y[0] - kr1*Y[1] - kc1*Y[1];
        const float d2 =  kc1*Y[1] - kDegradEgfr*Y[2] - kErkInbEgfr*Y[28]*Y[2];
        const float d3 = -kHer2_act*Y[3] + kr1*Y[4];
        STORE4(0, d0, d1, d2, d3);
        const float d4 =  kHer2_act*Y[3] - kr1*Y[4] - kc1*Y[4];
        const float d5 =  kc1*Y[4] - kDegradEgfr*Y[5] - kErkInbEgfr*Y[28]*Y[5];
        const float d6 = -kHer3_act*Y[6] + kr1*Y[7];
        const float d7 =  kHer3_act*Y[6] - kr1*Y[7] - kc1*Y[7];
        STORE4(1, d4, d5, d6, d7);
    }
    // --- Shc / Grb2 / Sos ---
    {
        const float d8  =  kc1*Y[7] - kDegradEgfr*Y[8] - kErkInbEgfr*Y[28]*Y[8];
        const float d9  = -ka1*Y[2]*Y[9];
        const float d10 =  ka1*Y[2]*Y[9] - kShcDephos*Y[11]*Y[10];
        const float d11 = -kptpDeg*Y[10]*Y[11];
        STORE4(2, d8, d9, d10, d11);
        const float d12 =  kGrb2CombShc*Y[10]*Y[2] - kSprtyInbGrb2*Y[26]*Y[12];
        const float d13 =  kSosCombGrb2*Y[12]*Y[10] - kErkPhosSos*Y[24]*Y[13];
        const float d14 = -ka1*Y[13]*Y[14];
        const float d15 =  ka1*Y[13]*Y[14];
        STORE4(3, d12, d13, d14, d15);
        const float d16 = -ka1*Y[13]*Y[16];
        const float d17 =  ka1*Y[13]*Y[16];
        const float d18 = -ka1*Y[13]*Y[18];
        const float d19 =  ka1*Y[13]*Y[18] - ka1*Y[19]*Y[20];
        STORE4(4, d16, d17, d18, d19);
    }
    // --- RAF with vemurafenib paradox (d61 held to group 15) ---
    float d61_h;
    {
        const float d20 = -ka1*Y[19]*Y[20];
        const float paradox = kParadoxCRAF * Vemurafenib * Y[61];
        const float akt_inh_craf = kAKT_CRAF_inhibit * Y[52] * Y[21];
        const float dimf = kDimerForm * Y[24] * Y[21] * Vemurafenib;
        const float dimd = kDimerDissoc * Y[61];
        const float d21 = -kpCraf*Y[19]*Y[21] + kErkPhosPcraf*Y[28]*Y[22]
                          + kPcrafDegrad*Y[22]*Y[35]
                          - dimf + dimd - akt_inh_craf;
        const float d22 =  kpCraf*Y[19]*Y[21] - kErkPhosPcraf*Y[28]*Y[22]
                          - kPcrafDegrad*Y[22]*Y[35] + paradox;
        const float d23 = -kBRAF_eff*Y[23]*Y[19] - dimf + dimd;
        STORE4(5, d20, d21, d22, d23);
        d61_h = dimf - dimd - kPcrafDegrad*Y[61]*Y[35];
        // --- MEK / ERK ---
        const float d24 = kBRAF_eff*Y[23]*Y[19] - kinbBraf*Y[24] - dimf + dimd;
        const float raf_to_mek = kpMek*Y[22] + kMekByBraf*Y[24] + kMekByCraf*Y[22];
        const float ksr_to_mek = kMekByKSR*Y[60];
        const float to_mek = (raf_to_mek + ksr_to_mek) * Y[25];
        const float d25 = -to_mek + kErkPhosMek*Y[28]*Y[26] + kMekDegrad*Y[26]*Y[34];
        const float d26 =  to_mek - kErkPhosMek*Y[28]*Y[26] - kMekDegrad*Y[26]*Y[34];
        const float d27 = -kpErk*Y[26]*Y[27] + kDuspInbErk*Y[30]*Y[28]
                          + kErkDeg*Y[28]*Y[33] + kErkDephos*Y[30]*Y[28];
        STORE4(6, d24, d25, d26, d27);
    }
    // --- ERK / DUSP / Sprouty feedback ---
    {
        const float d28 =  kpErk*Y[26]*Y[27] - kDuspInbErk*Y[30]*Y[28]
                          - kErkDeg*Y[28]*Y[33] - kErkDephos*Y[30]*Y[28];
        const float denom_dusp = 1.0f + km_Dusp / (kDusps + EPSC) * Y[28];
        const float d29 = km_Dusp*Y[28]/(denom_dusp + EPSC) - kDuspStop*Y[29]*Y[36] - kDuspDeg*Y[29]*Y[28];
        const float d30 = -kDuspStop*Y[29]*Y[30];
        const float denom_spry = 1.0f + km_Sprty / (kSproutyForm + EPSC) * Y[28];
        const float d31 = km_Sprty*Y[28]/(denom_spry + EPSC) - kSprtyComeDown*Y[31]*Y[32];
        STORE4(7, d28, d29, d30, d31);
        const float d32 = -kSprtyComeDown*Y[31]*Y[32];
        const float d33 = -kErkDeg*Y[28]*Y[33];
        const float d34 = -kMekDegrad*Y[26]*Y[34];
        const float d35 = -kPcrafDegrad*Y[22]*Y[35];
        STORE4(8, d32, d33, d34, d35);
    }
    // --- IGFR / IRS ---
    {
        const float d36 = -kDuspStop*Y[29]*Y[36];
        const float d37 = -ka1*Y[37] + kr1*Y[38];
        const float d38 =  ka1*Y[37] - kr1*Y[38] - kc1*Y[38];
        const float d39 =  kc1*Y[38] - kErkInbEgfr*Y[28]*Y[39];
        STORE4(9, d36, d37, d38, d39);
    }
    // --- IRS / p85 binding / PI3K (d67 held to group 16) ---
    float d67_h;
    {
        const float erk_irs = kERK_IRS_inhibit*Y[28]*Y[41];
        const float s6k_irs = kS6K_IRS_inhibit*Y[66]*Y[41];
        const float d40 = -ka1*Y[2]*Y[40] + erk_irs + s6k_irs;
        const float d41 =  ka1*Y[2]*Y[40] - erk_irs - s6k_irs;
        const float gab1 = 1.0f / (1.0f + kERK_GAB1_inhibit*Y[28]);
        const float bE = k_p85_bind_EGFR*Y[2]*Y[42]*gab1;
        const float b2 = k_p85_bind_Her2*Y[5]*Y[42]*gab1;
        const float b3 = k_p85_bind_Her3*Y[8]*Y[42]*gab1;
        const float bI = k_p85_bind_IGFR*Y[39]*Y[42];
        const float bP = k_p85_bind_PDGFR*Y[64]*Y[42];
        const float total_p85c = Y[43] + Y[44] + Y[45] + Y[46] + Y[67];
        const float d42 = -bE - b2 - b3 - bI - bP + k_p85_unbind*total_p85c;
        const float d43 = bE - k_p85_unbind*Y[43];
        STORE4(10, d40, d41, d42, d43);
        const float d44 = b2 - k_p85_unbind*Y[44];
        const float d45 = b3 - k_p85_unbind*Y[45];
        const float d46 = bI - k_p85_unbind*Y[46];
        d67_h = bP - k_p85_unbind*Y[67];
        const float pi3k_act = k_PI3K_recruit*total_p85c*Y[47] + kRAS_PI3K*Y[15]*Y[47];
        const float mtor_fb  = kMTOR_Feedback*Y[56]*Y[48];
        const float d47 = -pi3k_act + mtor_fb;
        STORE4(11, d44, d45, d46, d47);
        // --- PIP / PTEN / AKT ---
        const float d48 =  pi3k_act - mtor_fb;
        const float d49 = -k_PIP2_to_PIP3*Y[48]*Y[49] + k_PTEN*Y[51]*Y[50];
        const float d50 =  k_PIP2_to_PIP3*Y[48]*Y[49] - k_PTEN*Y[51]*Y[50];
        const float d51 =  kERK_PTEN_activate*Y[28] - kdegrad*Y[51];
        STORE4(12, d48, d49, d50, d51);
    }
    // --- AKT / TSC2 / mTOR / 4EBP1 ---
    {
        const float d52 =  kAkt*Y[50]*Y[53] - kdegradAKT*Y[52];
        const float d53 = -kAkt*Y[50]*Y[53] + kdegradAKT*Y[52];
        const float d54 = -kAKT_TSC2_phos*Y[52]*Y[54];
        const float d55 =  kAKT_TSC2_phos*Y[52]*Y[54] - kdegrad*Y[55];
        STORE4(13, d52, d53, d54, d55);
        const float d56 =  kb1*Y[52]*Y[57] - k43b1*Y[56];
        const float d57 = -kb1*Y[52]*Y[57] + k43b1*Y[56];
        const float d58 = -k4ebp1*Y[56]*Y[58] + k_4EBP1_dephos*Y[59];
        const float d59 =  k4ebp1*Y[56]*Y[58] - k_4EBP1_dephos*Y[59];
        STORE4(14, d56, d57, d58, d59);
    }
    // --- KSR / PDGFR (uses held d61) ---
    {
        const float d60 =  kKSRphos*Y[19]*Y[62]*tram_ksr - kKSRdephos*Y[60];
        const float d62 = -kKSRphos*Y[19]*Y[62]*tram_ksr + kKSRdephos*Y[60];
        const float d63 = -kPDGFR_act*Y[63];
        STORE4(15, d60, d61_h, d62, d63);
        // --- PDGFR / S6K (uses held d67) ---
        const float d64 =  kPDGFR_act*Y[63] - kDegradEgfr*Y[64];
        const float d65 = -kS6K_phos*Y[56]*Y[65] + kS6K_dephos*Y[66] - kERK_RSK_activate*Y[28]*Y[65];
        const float d66 =  kS6K_phos*Y[56]*Y[65] - kS6K_dephos*Y[66] + kERK_RSK_activate*Y[28]*Y[65];
        STORE4(16, d64, d65, d66, d67_h);
    }
#undef STORE4
}

extern "C" void kernel_launch(void* const* d_in, const int* in_sizes, int n_in,
                              void* d_out, int out_size, void* d_ws, size_t ws_size,
                              hipStream_t stream) {
    // setup_inputs order: t (1,), y (B*68,), params (75,)
    const float* y      = (const float*)d_in[1];
    const float* params = (const float*)d_in[2];
    float* out          = (float*)d_out;

    const int rows   = in_sizes[1] / NS;   // B = 524288
    const int blocks = rows / BLOCK;       // 2048

    MAPKPI3KODE_rhs_kernel<<<blocks, BLOCK, 0, stream>>>(y, params, out);
}

// Round 5
// 252.677 us; speedup vs baseline: 1.4264x; 1.4264x over previous
//
#include <hip/hip_runtime.h>
#include <math.h>

#define NS 68
#define WAVE 64
#define F4_PER_ROW 17      // 68 / 4
#define F4_PER_TILE (WAVE * F4_PER_ROW)   // 1088 float4 = 17408 B per wave tile
#define EPSC 1e-10f

// Round 5: async global->LDS staging (register-free MLP).
//  Evidence-driven design:
//  - Rounds 1-4: compiler collapses register-held loads to 40-92 VGPRs,
//    serializing memory (2.46 TB/s plateau). global_load_lds has NO dest
//    VGPRs -> all 17 x 1KB copies stay in flight regardless of heuristics.
//  - Round 4: scattered 16B global access amplifies bytes 2.5x. Here both
//    directions are lane-ordered 1KB bursts (full 64B lines only).
//  - One wave per block: __syncthreads() == pure vmcnt drain (no coupling);
//    LDS tile is the contiguous lane-ordered layout global_load_lds needs
//    (dest = wave-uniform base + lane*16; padding would break it).
//  - d written in place over the thread's own LDS row (Y register-resident
//    first; may-alias DS ordering is wave-internal, no barrier needed),
//    then lane-ordered float4 gather -> coalesced full-line stores.
__device__ __forceinline__ void async_copy16(const void* g, void* l) {
    __builtin_amdgcn_global_load_lds(
        (const __attribute__((address_space(1))) void*)g,
        (__attribute__((address_space(3))) void*)l,
        16 /*bytes*/, 0 /*offset*/, 0 /*aux*/);
}

__global__ __launch_bounds__(WAVE, 3) void MAPKPI3KODE_rhs_kernel(
    const float* __restrict__ y,
    const float* __restrict__ params,
    float* __restrict__ out)
{
    __shared__ float sm[WAVE * NS];    // 17408 B, unpadded (required by global_load_lds)
    const int lane = threadIdx.x;      // block == one wave
    const long tile_f4 = (long)blockIdx.x * F4_PER_TILE;

    const float4* __restrict__ y4 = (const float4*)y + tile_f4;

    // ---- stage in: 17 async 1KB copies, zero VGPRs, all in flight ----
    #pragma unroll
    for (int k = 0; k < F4_PER_ROW; ++k) {
        async_copy16(y4 + k * WAVE + lane, &sm[k * WAVE * 4]);
    }

    // ---- params (uniform scalar loads; overlap the DMA) ----
    const float ka1             = params[0];
    const float kr1             = params[1];
    const float kc1             = params[2];
    const float kpCraf          = params[3];
    const float kpMek           = params[4];
    const float kpErk           = params[5];
    const float kDegradEgfr     = params[6];
    const float kErkInbEgfr     = params[7];
    const float kShcDephos      = params[8];
    const float kptpDeg         = params[9];
    const float kGrb2CombShc    = params[10];
    const float kSprtyInbGrb2   = params[11];
    const float kSosCombGrb2    = params[12];
    const float kErkPhosSos     = params[13];
    const float kErkPhosPcraf   = params[14];
    const float kPcrafDegrad    = params[15];
    const float kErkPhosMek     = params[16];
    const float kMekDegrad      = params[17];
    const float kDuspInbErk     = params[18];
    const float kErkDeg         = params[19];
    const float kinbBraf        = params[20];
    const float kDuspStop       = params[21];
    const float kDusps          = params[22];
    const float kSproutyForm    = params[23];
    const float kSprtyComeDown  = params[24];
    const float kdegrad         = params[25];
    const float km_Dusp         = params[27];
    const float km_Sprty        = params[28];
    const float kErkDephos      = params[29];
    const float kDuspDeg        = params[30];
    const float kHer2_act       = params[31];
    const float kHer3_act       = params[32];
    const float k_p85_bind_EGFR = params[33];
    const float k_p85_bind_Her2 = params[34];
    const float k_p85_bind_Her3 = params[35];
    const float k_p85_bind_IGFR = params[36];
    const float k_p85_unbind    = params[37];
    const float k_PI3K_recruit  = params[38];
    const float kMTOR_Feedback  = params[39];
    const float k_PIP2_to_PIP3  = params[40];
    const float k_PTEN          = params[41];
    const float kAkt            = params[42];
    const float kdegradAKT      = params[43];
    const float kb1             = params[44];
    const float k43b1           = params[45];
    const float k4ebp1          = params[46];
    const float k_4EBP1_dephos  = params[47];
    const float kKSRphos        = params[48];
    const float kKSRdephos      = params[49];
    const float kMekByBraf      = params[50];
    const float kMekByCraf      = params[51];
    const float kMekByKSR       = params[52];
    const float Tram            = params[53];
    const float K_tram_KSR      = params[55];
    const float n_tram          = params[56];
    const float Vemurafenib     = params[57];
    const float kDimerForm      = params[58];
    const float kDimerDissoc    = params[59];
    const float kParadoxCRAF    = params[60];
    const float IC50_vem        = params[61];
    const float Hill_n_vem      = params[62];
    const float kPDGFR_act      = params[63];
    const float k_p85_bind_PDGFR= params[64];
    const float kS6K_phos       = params[65];
    const float kS6K_dephos     = params[66];
    const float kRAS_PI3K       = params[67];
    const float kERK_IRS_inhibit   = params[68];
    const float kERK_PTEN_activate = params[69];
    const float kAKT_CRAF_inhibit  = params[70];
    const float kS6K_IRS_inhibit   = params[71];
    const float kERK_GAB1_inhibit  = params[72];
    const float kAKT_TSC2_phos     = params[73];
    const float kERK_RSK_activate  = params[74];

    // uniform precomputes
    const float IC50_n   = powf(IC50_vem, Hill_n_vem);
    const float Vem_n    = powf(Vemurafenib, Hill_n_vem);
    const float kBRAF_eff = ka1 * IC50_n / (IC50_n + Vem_n + EPSC);
    const float Ktram_n  = powf(K_tram_KSR, n_tram);
    const float tram_n   = powf(Tram, n_tram);
    const float tram_ksr = Ktram_n / (Ktram_n + tram_n + EPSC);

    // ---- wait for DMA (single-wave block: barrier == vmcnt(0) drain) ----
    __syncthreads();

    // ---- read own row from LDS into registers, clip ----
    float Y[NS];
    {
        const float4* myf4 = (const float4*)&sm[lane * NS];   // lane*272 B, 16-aligned
        #pragma unroll
        for (int k = 0; k < F4_PER_ROW; ++k) {
            float4 v = myf4[k];
            Y[4*k+0] = fmaxf(v.x, 0.0f);
            Y[4*k+1] = fmaxf(v.y, 0.0f);
            Y[4*k+2] = fmaxf(v.z, 0.0f);
            Y[4*k+3] = fmaxf(v.w, 0.0f);
        }
    }

    // d groups written in place over the thread's own LDS row. Safe because
    // Y[] is fully register-resident before the first overwrite (compiler may
    // not re-read LDS it knows may have been clobbered).
#define PUT4(g, a, b, c, dd) do { \
        float4 _o; _o.x = (a); _o.y = (b); _o.z = (c); _o.w = (dd); \
        *(float4*)&sm[lane * NS + 4 * (g)] = _o; } while (0)

    // --- EGFR / Her2 / Her3 receptor modules ---
    {
        const float d0 = -ka1*Y[0] + kr1*Y[1];
        const float d1 =  ka1*Y[0] - kr1*Y[1] - kc1*Y[1];
        const float d2 =  kc1*Y[1] - kDegradEgfr*Y[2] - kErkInbEgfr*Y[28]*Y[2];
        const float d3 = -kHer2_act*Y[3] + kr1*Y[4];
        PUT4(0, d0, d1, d2, d3);
        const float d4 =  kHer2_act*Y[3] - kr1*Y[4] - kc1*Y[4];
        const float d5 =  kc1*Y[4] - kDegradEgfr*Y[5] - kErkInbEgfr*Y[28]*Y[5];
        const float d6 = -kHer3_act*Y[6] + kr1*Y[7];
        const float d7 =  kHer3_act*Y[6] - kr1*Y[7] - kc1*Y[7];
        PUT4(1, d4, d5, d6, d7);
    }
    // --- Shc / Grb2 / Sos ---
    {
        const float d8  =  kc1*Y[7] - kDegradEgfr*Y[8] - kErkInbEgfr*Y[28]*Y[8];
        const float d9  = -ka1*Y[2]*Y[9];
        const float d10 =  ka1*Y[2]*Y[9] - kShcDephos*Y[11]*Y[10];
        const float d11 = -kptpDeg*Y[10]*Y[11];
        PUT4(2, d8, d9, d10, d11);
        const float d12 =  kGrb2CombShc*Y[10]*Y[2] - kSprtyInbGrb2*Y[26]*Y[12];
        const float d13 =  kSosCombGrb2*Y[12]*Y[10] - kErkPhosSos*Y[24]*Y[13];
        const float d14 = -ka1*Y[13]*Y[14];
        const float d15 =  ka1*Y[13]*Y[14];
        PUT4(3, d12, d13, d14, d15);
        const float d16 = -ka1*Y[13]*Y[16];
        const float d17 =  ka1*Y[13]*Y[16];
        const float d18 = -ka1*Y[13]*Y[18];
        const float d19 =  ka1*Y[13]*Y[18] - ka1*Y[19]*Y[20];
        PUT4(4, d16, d17, d18, d19);
    }
    // --- RAF with vemurafenib paradox (d61 held) ---
    float d61_h;
    {
        const float d20 = -ka1*Y[19]*Y[20];
        const float paradox = kParadoxCRAF * Vemurafenib * Y[61];
        const float akt_inh_craf = kAKT_CRAF_inhibit * Y[52] * Y[21];
        const float dimf = kDimerForm * Y[24] * Y[21] * Vemurafenib;
        const float dimd = kDimerDissoc * Y[61];
        const float d21 = -kpCraf*Y[19]*Y[21] + kErkPhosPcraf*Y[28]*Y[22]
                          + kPcrafDegrad*Y[22]*Y[35]
                          - dimf + dimd - akt_inh_craf;
        const float d22 =  kpCraf*Y[19]*Y[21] - kErkPhosPcraf*Y[28]*Y[22]
                          - kPcrafDegrad*Y[22]*Y[35] + paradox;
        const float d23 = -kBRAF_eff*Y[23]*Y[19] - dimf + dimd;
        PUT4(5, d20, d21, d22, d23);
        d61_h = dimf - dimd - kPcrafDegrad*Y[61]*Y[35];
        // --- MEK / ERK ---
        const float d24 = kBRAF_eff*Y[23]*Y[19] - kinbBraf*Y[24] - dimf + dimd;
        const float raf_to_mek = kpMek*Y[22] + kMekByBraf*Y[24] + kMekByCraf*Y[22];
        const float ksr_to_mek = kMekByKSR*Y[60];
        const float to_mek = (raf_to_mek + ksr_to_mek) * Y[25];
        const float d25 = -to_mek + kErkPhosMek*Y[28]*Y[26] + kMekDegrad*Y[26]*Y[34];
        const float d26 =  to_mek - kErkPhosMek*Y[28]*Y[26] - kMekDegrad*Y[26]*Y[34];
        const float d27 = -kpErk*Y[26]*Y[27] + kDuspInbErk*Y[30]*Y[28]
                          + kErkDeg*Y[28]*Y[33] + kErkDephos*Y[30]*Y[28];
        PUT4(6, d24, d25, d26, d27);
    }
    // --- ERK / DUSP / Sprouty feedback ---
    {
        const float d28 =  kpErk*Y[26]*Y[27] - kDuspInbErk*Y[30]*Y[28]
                          - kErkDeg*Y[28]*Y[33] - kErkDephos*Y[30]*Y[28];
        const float denom_dusp = 1.0f + km_Dusp / (kDusps + EPSC) * Y[28];
        const float d29 = km_Dusp*Y[28]/(denom_dusp + EPSC) - kDuspStop*Y[29]*Y[36] - kDuspDeg*Y[29]*Y[28];
        const float d30 = -kDuspStop*Y[29]*Y[30];
        const float denom_spry = 1.0f + km_Sprty / (kSproutyForm + EPSC) * Y[28];
        const float d31 = km_Sprty*Y[28]/(denom_spry + EPSC) - kSprtyComeDown*Y[31]*Y[32];
        PUT4(7, d28, d29, d30, d31);
        const float d32 = -kSprtyComeDown*Y[31]*Y[32];
        const float d33 = -kErkDeg*Y[28]*Y[33];
        const float d34 = -kMekDegrad*Y[26]*Y[34];
        const float d35 = -kPcrafDegrad*Y[22]*Y[35];
        PUT4(8, d32, d33, d34, d35);
    }
    // --- IGFR / IRS ---
    {
        const float d36 = -kDuspStop*Y[29]*Y[36];
        const float d37 = -ka1*Y[37] + kr1*Y[38];
        const float d38 =  ka1*Y[37] - kr1*Y[38] - kc1*Y[38];
        const float d39 =  kc1*Y[38] - kErkInbEgfr*Y[28]*Y[39];
        PUT4(9, d36, d37, d38, d39);
    }
    // --- IRS / p85 binding / PI3K (d67 held) ---
    float d67_h;
    {
        const float erk_irs = kERK_IRS_inhibit*Y[28]*Y[41];
        const float s6k_irs = kS6K_IRS_inhibit*Y[66]*Y[41];
        const float d40 = -ka1*Y[2]*Y[40] + erk_irs + s6k_irs;
        const float d41 =  ka1*Y[2]*Y[40] - erk_irs - s6k_irs;
        const float gab1 = 1.0f / (1.0f + kERK_GAB1_inhibit*Y[28]);
        const float bE = k_p85_bind_EGFR*Y[2]*Y[42]*gab1;
        const float b2 = k_p85_bind_Her2*Y[5]*Y[42]*gab1;
        const float b3 = k_p85_bind_Her3*Y[8]*Y[42]*gab1;
        const float bI = k_p85_bind_IGFR*Y[39]*Y[42];
        const float bP = k_p85_bind_PDGFR*Y[64]*Y[42];
        const float total_p85c = Y[43] + Y[44] + Y[45] + Y[46] + Y[67];
        const float d42 = -bE - b2 - b3 - bI - bP + k_p85_unbind*total_p85c;
        const float d43 = bE - k_p85_unbind*Y[43];
        PUT4(10, d40, d41, d42, d43);
        const float d44 = b2 - k_p85_unbind*Y[44];
        const float d45 = b3 - k_p85_unbind*Y[45];
        const float d46 = bI - k_p85_unbind*Y[46];
        d67_h = bP - k_p85_unbind*Y[67];
        const float pi3k_act = k_PI3K_recruit*total_p85c*Y[47] + kRAS_PI3K*Y[15]*Y[47];
        const float mtor_fb  = kMTOR_Feedback*Y[56]*Y[48];
        const float d47 = -pi3k_act + mtor_fb;
        PUT4(11, d44, d45, d46, d47);
        // --- PIP / PTEN / AKT ---
        const float d48 =  pi3k_act - mtor_fb;
        const float d49 = -k_PIP2_to_PIP3*Y[48]*Y[49] + k_PTEN*Y[51]*Y[50];
        const float d50 =  k_PIP2_to_PIP3*Y[48]*Y[49] - k_PTEN*Y[51]*Y[50];
        const float d51 =  kERK_PTEN_activate*Y[28] - kdegrad*Y[51];
        PUT4(12, d48, d49, d50, d51);
    }
    // --- AKT / TSC2 / mTOR / 4EBP1 ---
    {
        const float d52 =  kAkt*Y[50]*Y[53] - kdegradAKT*Y[52];
        const float d53 = -kAkt*Y[50]*Y[53] + kdegradAKT*Y[52];
        const float d54 = -kAKT_TSC2_phos*Y[52]*Y[54];
        const float d55 =  kAKT_TSC2_phos*Y[52]*Y[54] - kdegrad*Y[55];
        PUT4(13, d52, d53, d54, d55);
        const float d56 =  kb1*Y[52]*Y[57] - k43b1*Y[56];
        const float d57 = -kb1*Y[52]*Y[57] + k43b1*Y[56];
        const float d58 = -k4ebp1*Y[56]*Y[58] + k_4EBP1_dephos*Y[59];
        const float d59 =  k4ebp1*Y[56]*Y[58] - k_4EBP1_dephos*Y[59];
        PUT4(14, d56, d57, d58, d59);
    }
    // --- KSR / PDGFR / S6K ---
    {
        const float d60 =  kKSRphos*Y[19]*Y[62]*tram_ksr - kKSRdephos*Y[60];
        const float d62 = -kKSRphos*Y[19]*Y[62]*tram_ksr + kKSRdephos*Y[60];
        const float d63 = -kPDGFR_act*Y[63];
        PUT4(15, d60, d61_h, d62, d63);
        const float d64 =  kPDGFR_act*Y[63] - kDegradEgfr*Y[64];
        const float d65 = -kS6K_phos*Y[56]*Y[65] + kS6K_dephos*Y[66] - kERK_RSK_activate*Y[28]*Y[65];
        const float d66 =  kS6K_phos*Y[56]*Y[65] - kS6K_dephos*Y[66] + kERK_RSK_activate*Y[28]*Y[65];
        PUT4(16, d64, d65, d66, d67_h);
    }
#undef PUT4

    // ---- stage out: lane-ordered gather -> coalesced 1KB full-line stores ----
    // Same-wave DS ordering (may-alias via sm) guarantees writes precede reads.
    {
        float4* __restrict__ o4 = (float4*)out + tile_f4;
        const float4* smf4 = (const float4*)sm;
        #pragma unroll
        for (int k = 0; k < F4_PER_ROW; ++k) {
            o4[k * WAVE + lane] = smf4[k * WAVE + lane];
        }
    }
}

extern "C" void kernel_launch(void* const* d_in, const int* in_sizes, int n_in,
                              void* d_out, int out_size, void* d_ws, size_t ws_size,
                              hipStream_t stream) {
    // setup_inputs order: t (1,), y (B*68,), params (75,)
    const float* y      = (const float*)d_in[1];
    const float* params = (const float*)d_in[2];
    float* out          = (float*)d_out;

    const int rows   = in_sizes[1] / NS;   // B = 524288
    const int blocks = rows / WAVE;        // 8192 single-wave blocks

    MAPKPI3KODE_rhs_kernel<<<blocks, WAVE, 0, stream>>>(y, params, out);
}